// Round 11
// baseline (102.459 us; speedup 1.0000x reference)
//
#include <hip/hip_runtime.h>
#include <stdint.h>

// ---------------------------------------------------------------------------
// SlidingAttentionModule: B=2, S=2048, D=1024, H=16, hd=64, window +-8
//   qkv = x @ w_qkv^T + b_qkv   (256^2 8-phase m201-template bf16 MFMA GEMM)
//   attn: MFMA-tiled 16-query x 32-key sliding window, no max-subtraction
//   out = ctx @ w_out^T + b_out (128^2 R5-proven bf16 MFMA GEMM, fp32 out)
// ---------------------------------------------------------------------------

typedef __bf16 bf16_t;
typedef bf16_t bf16x8 __attribute__((ext_vector_type(8)));
typedef unsigned short u16x8 __attribute__((ext_vector_type(8)));
typedef float f32x4 __attribute__((ext_vector_type(4)));

#define GLD16(g, l)                                                        \
  __builtin_amdgcn_global_load_lds(                                        \
      (const __attribute__((address_space(1))) void*)(g),                  \
      (__attribute__((address_space(3))) void*)(l), 16, 0, 0)

__device__ __forceinline__ unsigned short f2bf(float f) {
  unsigned int u = __float_as_uint(f);
  u += 0x7FFFu + ((u >> 16) & 1u);  // round-to-nearest-even
  return (unsigned short)(u >> 16);
}

__device__ __forceinline__ bf16x8 ld16(const unsigned short* p) {
  return __builtin_bit_cast(bf16x8, *reinterpret_cast<const u16x8*>(p));
}

// --- fp32 -> bf16 conversion of all three tensors, one launch ---------------
__global__ void cvt_all(const float* __restrict__ x, const float* __restrict__ wq,
                        const float* __restrict__ wo, unsigned short* __restrict__ xb,
                        unsigned short* __restrict__ wqb,
                        unsigned short* __restrict__ wob) {
  const int N0 = 1048576, N1 = 786432, N2 = 262144;  // float4 counts
  for (int i = blockIdx.x * blockDim.x + threadIdx.x; i < N0 + N1 + N2;
       i += gridDim.x * blockDim.x) {
    const float4* src;
    unsigned short* dst;
    int j;
    if (i < N0) { src = (const float4*)x; dst = xb; j = i; }
    else if (i < N0 + N1) { src = (const float4*)wq; dst = wqb; j = i - N0; }
    else { src = (const float4*)wo; dst = wob; j = i - N0 - N1; }
    const float4 f = src[j];
    ushort4 o;
    o.x = f2bf(f.x); o.y = f2bf(f.y); o.z = f2bf(f.z); o.w = f2bf(f.w);
    reinterpret_cast<ushort4*>(dst)[j] = o;
  }
}

// --- 256x256 8-phase QKV GEMM (m201 template port) --------------------------
// C[m,n] = sum_k A[m,k]*Bt[n,k] + bias[n]; scatter bf16 q/k [bh,s,64],
// v transposed [bh,d,2048].
// 8 waves: wr=wave>>2 (128-row half of C), wc=wave&3 (64-col quarter).
// LDS: sA/sB [2 buf][256 rows][64 k] ushort (32 KB each matrix per buf,
//   128 KB total). 16B slot s of row r holds global k-slot s^(r&7)
//   (R4-proven swizzle). Stage unit u covers rows [u*64,u*64+64):
//   thread tid -> row u*64+(tid>>3), global slot (tid&7)^((tid>>3)&7);
//   dest linear u*8KB + tid*16B; 8 threads span one 128B row segment.
// Per K-tile t (4 phases), reading buf[t&1], staging tile t+1 -> buf[~t&1]
//   (safe: that buffer's reader, tile t-1, finished at its last barrier):
//   p1: stage A(t+1) x4; vmcnt(4); barrier; ds_read kh0 {A m0-3, B n0-3};
//       lgkm(0); 16 MFMA; barrier
//   p2: stage B(t+1) x4; ds_read kh0 {A m4-7}; barrier; lgkm(0); 16 MFMA
//       (B kh0 frags reused from p1); barrier
//   p3: ds_read kh1 {A m0-3, B n0-3}; barrier; lgkm(0); 16 MFMA; barrier
//   p4: ds_read kh1 {A m4-7}; barrier; lgkm(0); 16 MFMA; barrier
// vmcnt stays counted (4) in steady state: tile t+1's loads span the whole
//   tile; p2-p4 read latency hides under the pre-MFMA barrier.
__global__ __launch_bounds__(512) void gemm_qkv(
    const unsigned short* __restrict__ A,   // [4096,1024] bf16 bits
    const unsigned short* __restrict__ Bt,  // [3072,1024] bf16 bits
    const float* __restrict__ bias,         // [3072]
    unsigned short* __restrict__ Cq, unsigned short* __restrict__ Ck,
    unsigned short* __restrict__ Cv) {
  __shared__ unsigned short sA[2][16384];
  __shared__ unsigned short sB[2][16384];

  const int K = 1024, T = 16;
  const int tid = threadIdx.x;
  const int wave = tid >> 6;
  const int lane = tid & 63;
  const int bid = blockIdx.x;
  const int m0 = (bid & 15) << 8;   // 16 m-tiles
  const int n0 = (bid >> 4) << 8;   // 12 n-tiles

  const int wr = wave >> 2;  // 0..1
  const int wc = wave & 3;   // 0..3

  f32x4 acc[8][4] = {};

  // staging source: unit u: thread -> row u*64+(tid>>3), slot (tid&7)^((tid>>3)&7)
  const int srow = tid >> 3;                           // 0..63 within unit
  const int sslot = ((tid & 7) ^ ((tid >> 3) & 7)) << 3;
  const unsigned short* Ag = A + (size_t)(m0 + srow) * K + sslot;
  const unsigned short* Bg = Bt + (size_t)(n0 + srow) * K + sslot;

  auto stageA = [&](int t, int b) {
#pragma unroll
    for (int u = 0; u < 4; ++u)
      GLD16(Ag + (size_t)(u * 64) * K + t * 64, &sA[b][u * 4096 + tid * 8]);
  };
  auto stageB = [&](int t, int b) {
#pragma unroll
    for (int u = 0; u < 4; ++u)
      GLD16(Bg + (size_t)(u * 64) * K + t * 64, &sB[b][u * 4096 + tid * 8]);
  };

  // prologue: tile 0 fully staged (8 loads)
  stageA(0, 0);
  stageB(0, 0);

  const int qr = lane & 15;
  const int kg = lane >> 4;
  const int x0 = (kg ^ (qr & 7)) << 3;        // kh0 slot (elem offset)
  const int x1 = ((4 | kg) ^ (qr & 7)) << 3;  // kh1 slot
  // A frag (m, kh): unit = wr*2+(m>>2); off = unit*4096 + ((m&3)*16+qr)*64 + x
  const int abase = wr * 8192 + qr * 64;
  // B frag (n, kh): off = wc*4096 + (n*16+qr)*64 + x
  const int bbase = wc * 4096 + qr * 64;

  bf16x8 af[4], bf[4];

  for (int t = 0; t < T; ++t) {
    const int b = t & 1;
    const unsigned short* sAb = sA[b];
    const unsigned short* sBb = sB[b];
    const int nb = b ^ 1;

    // ---------- phase 1: kh0, m0-3 ----------
    if (t + 1 < T) {
      stageA(t + 1, nb);
      asm volatile("s_waitcnt vmcnt(4)" ::: "memory");  // tile t landed
    } else {
      asm volatile("s_waitcnt vmcnt(0)" ::: "memory");
    }
    __builtin_amdgcn_s_barrier();  // every wave's tile-t loads landed
#pragma unroll
    for (int m = 0; m < 4; ++m)
      af[m] = ld16(&sAb[abase + (m >> 2) * 4096 + (m & 3) * 1024 + x0]);
#pragma unroll
    for (int n = 0; n < 4; ++n) bf[n] = ld16(&sBb[bbase + n * 1024 + x0]);
    asm volatile("s_waitcnt lgkmcnt(0)" ::: "memory");
    __builtin_amdgcn_sched_barrier(0);
    __builtin_amdgcn_s_setprio(1);
#pragma unroll
    for (int m = 0; m < 4; ++m)
#pragma unroll
      for (int n = 0; n < 4; ++n)
        acc[m][n] = __builtin_amdgcn_mfma_f32_16x16x32_bf16(af[m], bf[n],
                                                            acc[m][n], 0, 0, 0);
    __builtin_amdgcn_s_setprio(0);
    __builtin_amdgcn_s_barrier();

    // ---------- phase 2: kh0, m4-7 (B kh0 reused) ----------
    if (t + 1 < T) stageB(t + 1, nb);
#pragma unroll
    for (int m = 0; m < 4; ++m)
      af[m] = ld16(&sAb[abase + 4096 + m * 1024 + x0]);  // unit wr*2+1
    __builtin_amdgcn_s_barrier();  // reads drain under barrier
    asm volatile("s_waitcnt lgkmcnt(0)" ::: "memory");
    __builtin_amdgcn_sched_barrier(0);
    __builtin_amdgcn_s_setprio(1);
#pragma unroll
    for (int m = 0; m < 4; ++m)
#pragma unroll
      for (int n = 0; n < 4; ++n)
        acc[m + 4][n] = __builtin_amdgcn_mfma_f32_16x16x32_bf16(
            af[m], bf[n], acc[m + 4][n], 0, 0, 0);
    __builtin_amdgcn_s_setprio(0);
    __builtin_amdgcn_s_barrier();

    // ---------- phase 3: kh1, m0-3 ----------
#pragma unroll
    for (int m = 0; m < 4; ++m)
      af[m] = ld16(&sAb[abase + (m >> 2) * 4096 + (m & 3) * 1024 + x1]);
#pragma unroll
    for (int n = 0; n < 4; ++n) bf[n] = ld16(&sBb[bbase + n * 1024 + x1]);
    __builtin_amdgcn_s_barrier();
    asm volatile("s_waitcnt lgkmcnt(0)" ::: "memory");
    __builtin_amdgcn_sched_barrier(0);
    __builtin_amdgcn_s_setprio(1);
#pragma unroll
    for (int m = 0; m < 4; ++m)
#pragma unroll
      for (int n = 0; n < 4; ++n)
        acc[m][n] = __builtin_amdgcn_mfma_f32_16x16x32_bf16(af[m], bf[n],
                                                            acc[m][n], 0, 0, 0);
    __builtin_amdgcn_s_setprio(0);
    __builtin_amdgcn_s_barrier();

    // ---------- phase 4: kh1, m4-7 (B kh1 reused) ----------
#pragma unroll
    for (int m = 0; m < 4; ++m)
      af[m] = ld16(&sAb[abase + 4096 + m * 1024 + x1]);
    __builtin_amdgcn_s_barrier();
    asm volatile("s_waitcnt lgkmcnt(0)" ::: "memory");
    __builtin_amdgcn_sched_barrier(0);
    __builtin_amdgcn_s_setprio(1);
#pragma unroll
    for (int m = 0; m < 4; ++m)
#pragma unroll
      for (int n = 0; n < 4; ++n)
        acc[m + 4][n] = __builtin_amdgcn_mfma_f32_16x16x32_bf16(
            af[m], bf[n], acc[m + 4][n], 0, 0, 0);
    __builtin_amdgcn_s_setprio(0);
    __builtin_amdgcn_s_barrier();
  }

  // epilogue: C/D layout col = lane&15, row = (lane>>4)*4 + reg  [m89]
#pragma unroll
  for (int m = 0; m < 8; ++m) {
    const int row0 = m0 + wr * 128 + m * 16 + ((lane >> 4) << 2);
#pragma unroll
    for (int n = 0; n < 4; ++n) {
      const int col = n0 + wc * 64 + n * 16 + (lane & 15);
      const float bb = bias[col];
#pragma unroll
      for (int r = 0; r < 4; ++r) {
        const int mm = row0 + r;
        const float val = acc[m][n][r] + bb;
        const int b2 = mm >> 11, s = mm & 2047;
        const int which = col >> 10, nn = col & 1023;
        const int h = nn >> 6, d = nn & 63;
        const int bh = (b2 << 4) + h;
        const unsigned short vb = f2bf(val);
        if (which == 0)
          Cq[((size_t)(bh * 2048 + s)) * 64 + d] = vb;
        else if (which == 1)
          Ck[((size_t)(bh * 2048 + s)) * 64 + d] = vb;
        else
          Cv[((size_t)(bh * 64 + d)) * 2048 + s] = vb;
      }
    }
  }
}

// --- 128x128 R5-proven GEMM (out projection, fp32 out) ----------------------
__global__ __launch_bounds__(256, 2) void gemm_bt(
    const unsigned short* __restrict__ A,   // [M,K] bf16 bits
    const unsigned short* __restrict__ Bt,  // [N,K] bf16 bits
    const float* __restrict__ bias,         // [N]
    float* __restrict__ Cp, int M, int N, int K, int gny) {
  __shared__ unsigned short sA[2][8192];
  __shared__ unsigned short sB[2][8192];

  const int tid = threadIdx.x;
  const int wave = tid >> 6;
  const int lane = tid & 63;

  const int nwg = gridDim.x;
  const int bid = blockIdx.x;
  const int cw = (nwg >> 3) / gny;
  const int xcd = bid & 7;
  const int idx = bid >> 3;
  const int m0 = (xcd * cw + idx % cw) * 128;
  const int n0 = (idx / cw) * 128;

  const int wr = wave >> 1;
  const int wc = wave & 1;

  f32x4 acc[4][4] = {};

  const int srow = (wave << 3) + (lane >> 3);
  const int sslot = ((lane & 7) ^ (lane >> 3)) << 3;
  const unsigned short* Ag = A + (size_t)(m0 + srow) * K + sslot;
  const unsigned short* Bg = Bt + (size_t)(n0 + srow) * K + sslot;
  const int wdst = wave * 512;

  const int T = K >> 6;

  auto stage = [&](int t, int b) {
#pragma unroll
    for (int r = 0; r < 4; ++r) {
      GLD16(Ag + (size_t)(r * 32) * K + t * 64, &sA[b][r * 2048 + wdst]);
      GLD16(Bg + (size_t)(r * 32) * K + t * 64, &sB[b][r * 2048 + wdst]);
    }
  };

  stage(0, 0);
  stage(1, 1);

  const int kg = lane >> 4;
  const int l7 = lane & 7;
  const int arr = wr * 64 + (lane & 15);
  const int brr = wc * 64 + (lane & 15);

  for (int t = 0; t < T; ++t) {
    if (t < T - 1)
      asm volatile("s_waitcnt vmcnt(8)" ::: "memory");
    else
      asm volatile("s_waitcnt vmcnt(0)" ::: "memory");
    __builtin_amdgcn_s_barrier();

    const int b = t & 1;
    const unsigned short* sAb = sA[b];
    const unsigned short* sBb = sB[b];
    bf16x8 af[2][4], bfr[2][4];
#pragma unroll
    for (int st = 0; st < 2; ++st) {
#pragma unroll
      for (int f = 0; f < 4; ++f) {
        const int se = ((st << 2) | kg) ^ l7;
        af[st][f] = ld16(&sAb[(arr + f * 16) * 64 + (se << 3)]);
        bfr[st][f] = ld16(&sBb[(brr + f * 16) * 64 + (se << 3)]);
      }
    }
    asm volatile("s_waitcnt lgkmcnt(0)" ::: "memory");
    __builtin_amdgcn_sched_barrier(0);
    __builtin_amdgcn_s_barrier();

    if (t + 2 < T) stage(t + 2, b);

#pragma unroll
    for (int st = 0; st < 2; ++st)
#pragma unroll
      for (int i = 0; i < 4; ++i)
#pragma unroll
        for (int j = 0; j < 4; ++j)
          acc[i][j] = __builtin_amdgcn_mfma_f32_16x16x32_bf16(
              af[st][i], bfr[st][j], acc[i][j], 0, 0, 0);
  }

#pragma unroll
  for (int i = 0; i < 4; ++i) {
    const int row0 = m0 + wr * 64 + i * 16 + ((lane >> 4) << 2);
#pragma unroll
    for (int j = 0; j < 4; ++j) {
      const int col = n0 + wc * 64 + j * 16 + (lane & 15);
      const float bb = bias[col];
#pragma unroll
      for (int r = 0; r < 4; ++r)
        Cp[(size_t)(row0 + r) * N + col] = acc[i][j][r] + bb;
    }
  }
}

// --- MFMA sliding attention: 1 wave = 16 queries x 32-key window ------------
// Q,K: [bh, s, 64] bf16.  Vt: [bh, d, 2048] bf16.  ctx out: [b, s, 1024] bf16.
__global__ __launch_bounds__(256) void attn_mfma(
    const unsigned short* __restrict__ Qb, const unsigned short* __restrict__ Kb,
    const unsigned short* __restrict__ Vt, unsigned short* __restrict__ ctx) {
  __shared__ unsigned short P[4][16][40];  // per-wave P tile, padded stride 40
  const int wave = threadIdx.x >> 6;
  const int lane = threadIdx.x & 63;
  const int gw = (blockIdx.x << 2) + wave;
  const int bh = gw >> 7;           // 0..31
  const int i0 = (gw & 127) << 4;   // query tile start
  const int qr = lane & 15;
  const int kg = lane >> 4;         // 0..3
  const int kc = kg << 3;           // k-offset

  const size_t qbase = ((size_t)(bh * 2048 + i0 + qr)) * 64;
  const bf16x8 aq0 = ld16(Qb + qbase + kc);
  const bf16x8 aq1 = ld16(Qb + qbase + 32 + kc);

  f32x4 sc0 = {0.f, 0.f, 0.f, 0.f}, sc1 = {0.f, 0.f, 0.f, 0.f};
  {
    const int ka0 = i0 - 8 + qr;
    const int ka1 = ka0 + 16;
    const int kcl0 = min(max(ka0, 0), 2047);
    const int kcl1 = min(max(ka1, 0), 2047);
    const unsigned short* K0 = Kb + ((size_t)(bh * 2048 + kcl0)) * 64;
    const unsigned short* K1 = Kb + ((size_t)(bh * 2048 + kcl1)) * 64;
    sc0 = __builtin_amdgcn_mfma_f32_16x16x32_bf16(aq0, ld16(K0 + kc), sc0, 0, 0, 0);
    sc0 = __builtin_amdgcn_mfma_f32_16x16x32_bf16(aq1, ld16(K0 + 32 + kc), sc0, 0, 0, 0);
    sc1 = __builtin_amdgcn_mfma_f32_16x16x32_bf16(aq0, ld16(K1 + kc), sc1, 0, 0, 0);
    sc1 = __builtin_amdgcn_mfma_f32_16x16x32_bf16(aq1, ld16(K1 + 32 + kc), sc1, 0, 0, 0);
  }

  unsigned short* Pw = &P[wave][0][0];
  float lsum[4];
#pragma unroll
  for (int r = 0; r < 4; ++r) {
    const int q = (kg << 2) + r;
    const int key0 = qr, key1 = 16 + qr;
    const int ka0 = i0 - 8 + key0, ka1 = i0 - 8 + key1;
    const bool v0 = (q <= key0) && (key0 <= q + 16) && (ka0 >= 0) && (ka0 < 2048);
    const bool v1 = (q <= key1) && (key1 <= q + 16) && (ka1 >= 0) && (ka1 < 2048);
    const float e0 = v0 ? __expf(sc0[r] * 0.125f) : 0.f;
    const float e1 = v1 ? __expf(sc1[r] * 0.125f) : 0.f;
    Pw[q * 40 + key0] = f2bf(e0);
    Pw[q * 40 + key1] = f2bf(e1);
    float s = e0 + e1;
#pragma unroll
    for (int off = 1; off < 16; off <<= 1) s += __shfl_xor(s, off);
    lsum[r] = s;
  }

  const bf16x8 pa = ld16(&Pw[qr * 40 + kc]);

  const int base_s = min(max(i0 - 8 + kc, 0), 2040);
  f32x4 o[4];
  const f32x4 zero = {0.f, 0.f, 0.f, 0.f};
#pragma unroll
  for (int t2 = 0; t2 < 4; ++t2) {
    const unsigned short* Vr =
        Vt + ((size_t)(bh * 64 + t2 * 16 + qr)) * 2048 + base_s;
    o[t2] = __builtin_amdgcn_mfma_f32_16x16x32_bf16(pa, ld16(Vr), zero, 0, 0, 0);
  }

  const int b = bh >> 4, h = bh & 15;
  float rinv[4];
#pragma unroll
  for (int r = 0; r < 4; ++r) rinv[r] = 1.0f / lsum[r];
#pragma unroll
  for (int t2 = 0; t2 < 4; ++t2) {
#pragma unroll
    for (int r = 0; r < 4; ++r) {
      const int q = (kg << 2) + r;
      const int d = t2 * 16 + qr;
      ctx[((size_t)(b * 2048 + i0 + q)) * 1024 + (h << 6) + d] =
          f2bf(o[t2][r] * rinv[r]);
    }
  }
}

// ---------------------------------------------------------------------------
extern "C" void kernel_launch(void* const* d_in, const int* in_sizes, int n_in,
                              void* d_out, int out_size, void* d_ws,
                              size_t ws_size, hipStream_t stream) {
  const float* x = (const float*)d_in[0];      // [2,2048,1024]
  // d_in[1] token_ids: unused by reference
  const float* w_qkv = (const float*)d_in[2];  // [3072,1024]
  const float* b_qkv = (const float*)d_in[3];  // [3072]
  const float* w_out = (const float*)d_in[4];  // [1024,1024]
  const float* b_out = (const float*)d_in[5];  // [1024]
  float* out = (float*)d_out;                  // [2,2048,1024] fp32

  char* ws = (char*)d_ws;
  unsigned short* xb    = (unsigned short*)(ws + 0);         // 8 MB
  unsigned short* wqkvb = (unsigned short*)(ws + 8388608);   // 6 MB
  unsigned short* woutb = (unsigned short*)(ws + 14680064);  // 2 MB
  unsigned short* Qb    = (unsigned short*)(ws + 16777216);  // 8 MB [bh,s,64]
  unsigned short* Kb    = (unsigned short*)(ws + 25165824);  // 8 MB [bh,s,64]
  unsigned short* Vt    = (unsigned short*)(ws + 33554432);  // 8 MB [bh,d,2048]
  unsigned short* ctxb  = (unsigned short*)(ws + 41943040);  // 8 MB [b,s,1024]

  // fp32 -> bf16 conversions, one launch (grid-stride)
  cvt_all<<<2048, 256, 0, stream>>>(x, w_qkv, w_out, xb, wqkvb, woutb);

  // QKV projection: M=4096, N=3072, K=1024 -> bf16 Q/K/Vt scatter
  // 256^2 tiles, 8-phase schedule: 16 x 12 = 192 blocks, 512 threads
  gemm_qkv<<<192, 512, 0, stream>>>(xb, wqkvb, b_qkv, Qb, Kb, Vt);

  // sliding attention: 4096 waves (16 queries each), 4 waves/block
  attn_mfma<<<1024, 256, 0, stream>>>(Qb, Kb, Vt, ctxb);

  // out projection: M=4096, N=1024, K=1024 -> fp32 d_out (256 blocks, gny=8)
  gemm_bt<<<256, 256, 0, stream>>>(ctxb, woutb, b_out, out, 4096, 1024, 1024, 8);
}

// Round 12
// 74.702 us; speedup vs baseline: 1.3716x; 1.3716x over previous
//
#include <hip/hip_runtime.h>
#include <stdint.h>

// ---------------------------------------------------------------------------
// SlidingAttentionModule: B=2, S=2048, D=1024, H=16, hd=64, window +-8
//   qkv = x @ w_qkv^T + b_qkv   (128^2 BK=32 3-deep GEMM; V epilogue now
//                                LDS-transposed -> coalesced Vt writes)
//   attn: MFMA-tiled 16-query x 32-key sliding window, no max-subtraction
//   out = ctx @ w_out^T + b_out (128^2 BK=64 2-deep R5-proven GEMM, fp32 out)
// ---------------------------------------------------------------------------

typedef __bf16 bf16_t;
typedef bf16_t bf16x8 __attribute__((ext_vector_type(8)));
typedef unsigned short u16x8 __attribute__((ext_vector_type(8)));
typedef float f32x4 __attribute__((ext_vector_type(4)));

#define GLD16(g, l)                                                        \
  __builtin_amdgcn_global_load_lds(                                        \
      (const __attribute__((address_space(1))) void*)(g),                  \
      (__attribute__((address_space(3))) void*)(l), 16, 0, 0)

__device__ __forceinline__ unsigned short f2bf(float f) {
  unsigned int u = __float_as_uint(f);
  u += 0x7FFFu + ((u >> 16) & 1u);  // round-to-nearest-even
  return (unsigned short)(u >> 16);
}

__device__ __forceinline__ bf16x8 ld16(const unsigned short* p) {
  return __builtin_bit_cast(bf16x8, *reinterpret_cast<const u16x8*>(p));
}

// --- fp32 -> bf16 conversion of all three tensors, one launch ---------------
__global__ void cvt_all(const float* __restrict__ x, const float* __restrict__ wq,
                        const float* __restrict__ wo, unsigned short* __restrict__ xb,
                        unsigned short* __restrict__ wqb,
                        unsigned short* __restrict__ wob) {
  const int N0 = 1048576, N1 = 786432, N2 = 262144;  // float4 counts
  for (int i = blockIdx.x * blockDim.x + threadIdx.x; i < N0 + N1 + N2;
       i += gridDim.x * blockDim.x) {
    const float4* src;
    unsigned short* dst;
    int j;
    if (i < N0) { src = (const float4*)x; dst = xb; j = i; }
    else if (i < N0 + N1) { src = (const float4*)wq; dst = wqb; j = i - N0; }
    else { src = (const float4*)wo; dst = wob; j = i - N0 - N1; }
    const float4 f = src[j];
    ushort4 o;
    o.x = f2bf(f.x); o.y = f2bf(f.y); o.z = f2bf(f.z); o.w = f2bf(f.w);
    reinterpret_cast<ushort4*>(dst)[j] = o;
  }
}

// --- 128x128 BK=32 3-deep QKV GEMM (R10 K-loop, new V epilogue) --------------
// C[m,n] = sum_k A[m,k]*Bt[n,k] + bias[n]; scatter bf16 q/k [bh,s,64];
// V region (n0>=2048): transpose tile in LDS, write Vt [bh,d,2048] in
// coalesced 256B segments (was: 4.2M isolated 2B stride-4KB stores).
// K-loop identical to R10: 3 buffers (48KB, 3 blocks/CU), counted vmcnt(8),
// raw barrier pair, stage(t+3) after read-drain; R10-proven BK=32 swizzle.
__global__ __launch_bounds__(256) void gemm_qkv(
    const unsigned short* __restrict__ A,   // [4096,1024] bf16 bits
    const unsigned short* __restrict__ Bt,  // [3072,1024] bf16 bits
    const float* __restrict__ bias,         // [3072]
    unsigned short* __restrict__ Cq, unsigned short* __restrict__ Ck,
    unsigned short* __restrict__ Cv) {
  __shared__ unsigned short smem[24576];  // K-loop: sA 3x4096 | sB 3x4096
                                          // epilogue (V): ldsT [128][136]
  const int K = 1024;
  const int tid = threadIdx.x;
  const int wave = tid >> 6;
  const int lane = tid & 63;
  const int m0 = blockIdx.x << 7;  // 32 m-tiles
  const int n0 = blockIdx.y << 7;  // 24 n-tiles

  const int wr = wave >> 1;
  const int wc = wave & 1;

  f32x4 acc[4][4] = {};

  // staging source: lane u -> row wave*16+(u>>2) (+r*64), chunk (u&3)^((u>>3)&3)
  const int srow = (wave << 4) + (lane >> 2);
  const int sslot = (((lane & 3) ^ ((lane >> 3) & 3)) << 3);
  const unsigned short* Ag = A + (size_t)(m0 + srow) * K + sslot;
  const unsigned short* Bg = Bt + (size_t)(n0 + srow) * K + sslot;
  const int wdst = wave * 512;  // ushort offset; +r*2048; +lane*8 implicit

  auto stage = [&](int t, int b) {
#pragma unroll
    for (int r = 0; r < 2; ++r) {
      GLD16(Ag + (size_t)(r * 64) * K + t * 32, &smem[b * 4096 + r * 2048 + wdst]);
      GLD16(Bg + (size_t)(r * 64) * K + t * 32,
            &smem[12288 + b * 4096 + r * 2048 + wdst]);
    }
  };

  // prologue: 3 K-tiles in flight (12 loads/thread)
  stage(0, 0);
  stage(1, 1);
  stage(2, 2);

  const int qr = lane & 15;
  const int kg = lane >> 4;
  const int geff8 = ((kg ^ ((qr >> 1) & 3)) << 3);
  const int ar = wr * 64 + qr;
  const int br = wc * 64 + qr;

  for (int t = 0; t < 32; ++t) {
    if (t < 30)
      asm volatile("s_waitcnt vmcnt(8)" ::: "memory");
    else if (t == 30)
      asm volatile("s_waitcnt vmcnt(4)" ::: "memory");
    else
      asm volatile("s_waitcnt vmcnt(0)" ::: "memory");
    __builtin_amdgcn_s_barrier();  // all waves' tile-t loads landed

    const int b = t % 3;
    const unsigned short* sAb = &smem[b * 4096];
    const unsigned short* sBb = &smem[12288 + b * 4096];

    bf16x8 af[4], bf[4];
#pragma unroll
    for (int f = 0; f < 4; ++f) {
      af[f] = ld16(&sAb[(ar + f * 16) * 32 + geff8]);
      bf[f] = ld16(&sBb[(br + f * 16) * 32 + geff8]);
    }
    asm volatile("s_waitcnt lgkmcnt(0)" ::: "memory");  // frags in regs
    __builtin_amdgcn_sched_barrier(0);                  // rule #18
    __builtin_amdgcn_s_barrier();  // all waves done reading buf b

    if (t + 3 < 32) stage(t + 3, b);  // overwrite safe; hidden by MFMAs

    __builtin_amdgcn_s_setprio(1);
#pragma unroll
    for (int i = 0; i < 4; ++i)
#pragma unroll
      for (int j = 0; j < 4; ++j)
        acc[i][j] = __builtin_amdgcn_mfma_f32_16x16x32_bf16(af[i], bf[j],
                                                            acc[i][j], 0, 0, 0);
    __builtin_amdgcn_s_setprio(0);
  }

  // epilogue: C/D layout col = lane&15, row = (lane>>4)*4 + reg  [m89]
  if (n0 < 2048) {
    // Q/K region: direct write (16-lane 32B chunks, as before)
#pragma unroll
    for (int i = 0; i < 4; ++i) {
      const int row0 = m0 + wr * 64 + i * 16 + ((lane >> 4) << 2);
#pragma unroll
      for (int j = 0; j < 4; ++j) {
        const int col = n0 + wc * 64 + j * 16 + (lane & 15);
        const float bb = bias[col];
#pragma unroll
        for (int r = 0; r < 4; ++r) {
          const int mm = row0 + r;
          const int b2 = mm >> 11, s = mm & 2047;
          const int which = col >> 10, nn = col & 1023;
          const int h = nn >> 6, d = nn & 63;
          const int bh = (b2 << 4) + h;
          const unsigned short vb = f2bf(acc[i][j][r] + bb);
          if (which == 0)
            Cq[((size_t)(bh * 2048 + s)) * 64 + d] = vb;
          else
            Ck[((size_t)(bh * 2048 + s)) * 64 + d] = vb;
        }
      }
    }
  } else {
    // V region: transpose via LDS, then coalesced Vt writes.
    __syncthreads();  // K-loop LDS traffic fully retired; smem reusable
    unsigned short(*ldsT)[136] = (unsigned short(*)[136])smem;
#pragma unroll
    for (int i = 0; i < 4; ++i) {
      const int rl0 = wr * 64 + i * 16 + ((lane >> 4) << 2);  // local row
#pragma unroll
      for (int j = 0; j < 4; ++j) {
        const int cl = wc * 64 + j * 16 + (lane & 15);  // local col
        const float bb = bias[n0 + cl];
        ushort4 v4;
        v4.x = f2bf(acc[i][j][0] + bb);
        v4.y = f2bf(acc[i][j][1] + bb);
        v4.z = f2bf(acc[i][j][2] + bb);
        v4.w = f2bf(acc[i][j][3] + bb);
        *reinterpret_cast<ushort4*>(&ldsT[cl][rl0]) = v4;  // b64, 2-way free
      }
    }
    __syncthreads();
    // thread t, iter it: col cl=(t>>4)+it*16, s-chunk j=t&15.
    // 16 lanes (fixed cl) write 16x16B consecutive = 256B coalesced segment.
    const int b2 = m0 >> 11;
    const int sbase = m0 & 2047;
    const int jj = tid & 15;
#pragma unroll
    for (int it = 0; it < 8; ++it) {
      const int cl = (tid >> 4) + it * 16;
      const int nn = (n0 + cl) & 1023;
      const int bh = (b2 << 4) + (nn >> 6);
      const int d = nn & 63;
      const u16x8 v = *reinterpret_cast<const u16x8*>(&ldsT[cl][jj * 8]);
      *reinterpret_cast<u16x8*>(
          &Cv[((size_t)(bh * 64 + d)) * 2048 + sbase + jj * 8]) = v;
    }
  }
}

// --- 128x128 R5-proven GEMM (out projection, fp32 out) ----------------------
__global__ __launch_bounds__(256, 2) void gemm_bt(
    const unsigned short* __restrict__ A,   // [M,K] bf16 bits
    const unsigned short* __restrict__ Bt,  // [N,K] bf16 bits
    const float* __restrict__ bias,         // [N]
    float* __restrict__ Cp, int M, int N, int K, int gny) {
  __shared__ unsigned short sA[2][8192];
  __shared__ unsigned short sB[2][8192];

  const int tid = threadIdx.x;
  const int wave = tid >> 6;
  const int lane = tid & 63;

  const int nwg = gridDim.x;
  const int bid = blockIdx.x;
  const int cw = (nwg >> 3) / gny;
  const int xcd = bid & 7;
  const int idx = bid >> 3;
  const int m0 = (xcd * cw + idx % cw) * 128;
  const int n0 = (idx / cw) * 128;

  const int wr = wave >> 1;
  const int wc = wave & 1;

  f32x4 acc[4][4] = {};

  const int srow = (wave << 3) + (lane >> 3);
  const int sslot = ((lane & 7) ^ (lane >> 3)) << 3;
  const unsigned short* Ag = A + (size_t)(m0 + srow) * K + sslot;
  const unsigned short* Bg = Bt + (size_t)(n0 + srow) * K + sslot;
  const int wdst = wave * 512;

  const int T = K >> 6;

  auto stage = [&](int t, int b) {
#pragma unroll
    for (int r = 0; r < 4; ++r) {
      GLD16(Ag + (size_t)(r * 32) * K + t * 64, &sA[b][r * 2048 + wdst]);
      GLD16(Bg + (size_t)(r * 32) * K + t * 64, &sB[b][r * 2048 + wdst]);
    }
  };

  stage(0, 0);
  stage(1, 1);

  const int kg = lane >> 4;
  const int l7 = lane & 7;
  const int arr = wr * 64 + (lane & 15);
  const int brr = wc * 64 + (lane & 15);

  for (int t = 0; t < T; ++t) {
    if (t < T - 1)
      asm volatile("s_waitcnt vmcnt(8)" ::: "memory");
    else
      asm volatile("s_waitcnt vmcnt(0)" ::: "memory");
    __builtin_amdgcn_s_barrier();

    const int b = t & 1;
    const unsigned short* sAb = sA[b];
    const unsigned short* sBb = sB[b];
    bf16x8 af[2][4], bfr[2][4];
#pragma unroll
    for (int st = 0; st < 2; ++st) {
#pragma unroll
      for (int f = 0; f < 4; ++f) {
        const int se = ((st << 2) | kg) ^ l7;
        af[st][f] = ld16(&sAb[(arr + f * 16) * 64 + (se << 3)]);
        bfr[st][f] = ld16(&sBb[(brr + f * 16) * 64 + (se << 3)]);
      }
    }
    asm volatile("s_waitcnt lgkmcnt(0)" ::: "memory");
    __builtin_amdgcn_sched_barrier(0);
    __builtin_amdgcn_s_barrier();

    if (t + 2 < T) stage(t + 2, b);

#pragma unroll
    for (int st = 0; st < 2; ++st)
#pragma unroll
      for (int i = 0; i < 4; ++i)
#pragma unroll
        for (int j = 0; j < 4; ++j)
          acc[i][j] = __builtin_amdgcn_mfma_f32_16x16x32_bf16(
              af[st][i], bfr[st][j], acc[i][j], 0, 0, 0);
  }

#pragma unroll
  for (int i = 0; i < 4; ++i) {
    const int row0 = m0 + wr * 64 + i * 16 + ((lane >> 4) << 2);
#pragma unroll
    for (int j = 0; j < 4; ++j) {
      const int col = n0 + wc * 64 + j * 16 + (lane & 15);
      const float bb = bias[col];
#pragma unroll
      for (int r = 0; r < 4; ++r)
        Cp[(size_t)(row0 + r) * N + col] = acc[i][j][r] + bb;
    }
  }
}

// --- MFMA sliding attention: 1 wave = 16 queries x 32-key window ------------
// Q,K: [bh, s, 64] bf16.  Vt: [bh, d, 2048] bf16.  ctx out: [b, s, 1024] bf16.
__global__ __launch_bounds__(256) void attn_mfma(
    const unsigned short* __restrict__ Qb, const unsigned short* __restrict__ Kb,
    const unsigned short* __restrict__ Vt, unsigned short* __restrict__ ctx) {
  __shared__ unsigned short P[4][16][40];  // per-wave P tile, padded stride 40
  const int wave = threadIdx.x >> 6;
  const int lane = threadIdx.x & 63;
  const int gw = (blockIdx.x << 2) + wave;
  const int bh = gw >> 7;           // 0..31
  const int i0 = (gw & 127) << 4;   // query tile start
  const int qr = lane & 15;
  const int kg = lane >> 4;         // 0..3
  const int kc = kg << 3;           // k-offset

  const size_t qbase = ((size_t)(bh * 2048 + i0 + qr)) * 64;
  const bf16x8 aq0 = ld16(Qb + qbase + kc);
  const bf16x8 aq1 = ld16(Qb + qbase + 32 + kc);

  f32x4 sc0 = {0.f, 0.f, 0.f, 0.f}, sc1 = {0.f, 0.f, 0.f, 0.f};
  {
    const int ka0 = i0 - 8 + qr;
    const int ka1 = ka0 + 16;
    const int kcl0 = min(max(ka0, 0), 2047);
    const int kcl1 = min(max(ka1, 0), 2047);
    const unsigned short* K0 = Kb + ((size_t)(bh * 2048 + kcl0)) * 64;
    const unsigned short* K1 = Kb + ((size_t)(bh * 2048 + kcl1)) * 64;
    sc0 = __builtin_amdgcn_mfma_f32_16x16x32_bf16(aq0, ld16(K0 + kc), sc0, 0, 0, 0);
    sc0 = __builtin_amdgcn_mfma_f32_16x16x32_bf16(aq1, ld16(K0 + 32 + kc), sc0, 0, 0, 0);
    sc1 = __builtin_amdgcn_mfma_f32_16x16x32_bf16(aq0, ld16(K1 + kc), sc1, 0, 0, 0);
    sc1 = __builtin_amdgcn_mfma_f32_16x16x32_bf16(aq1, ld16(K1 + 32 + kc), sc1, 0, 0, 0);
  }

  unsigned short* Pw = &P[wave][0][0];
  float lsum[4];
#pragma unroll
  for (int r = 0; r < 4; ++r) {
    const int q = (kg << 2) + r;
    const int key0 = qr, key1 = 16 + qr;
    const int ka0 = i0 - 8 + key0, ka1 = i0 - 8 + key1;
    const bool v0 = (q <= key0) && (key0 <= q + 16) && (ka0 >= 0) && (ka0 < 2048);
    const bool v1 = (q <= key1) && (key1 <= q + 16) && (ka1 >= 0) && (ka1 < 2048);
    const float e0 = v0 ? __expf(sc0[r] * 0.125f) : 0.f;
    const float e1 = v1 ? __expf(sc1[r] * 0.125f) : 0.f;
    Pw[q * 40 + key0] = f2bf(e0);
    Pw[q * 40 + key1] = f2bf(e1);
    float s = e0 + e1;
#pragma unroll
    for (int off = 1; off < 16; off <<= 1) s += __shfl_xor(s, off);
    lsum[r] = s;
  }

  const bf16x8 pa = ld16(&Pw[qr * 40 + kc]);

  const int base_s = min(max(i0 - 8 + kc, 0), 2040);
  f32x4 o[4];
  const f32x4 zero = {0.f, 0.f, 0.f, 0.f};
#pragma unroll
  for (int t2 = 0; t2 < 4; ++t2) {
    const unsigned short* Vr =
        Vt + ((size_t)(bh * 64 + t2 * 16 + qr)) * 2048 + base_s;
    o[t2] = __builtin_amdgcn_mfma_f32_16x16x32_bf16(pa, ld16(Vr), zero, 0, 0, 0);
  }

  const int b = bh >> 4, h = bh & 15;
  float rinv[4];
#pragma unroll
  for (int r = 0; r < 4; ++r) rinv[r] = 1.0f / lsum[r];
#pragma unroll
  for (int t2 = 0; t2 < 4; ++t2) {
#pragma unroll
    for (int r = 0; r < 4; ++r) {
      const int q = (kg << 2) + r;
      const int d = t2 * 16 + qr;
      ctx[((size_t)(b * 2048 + i0 + q)) * 1024 + (h << 6) + d] =
          f2bf(o[t2][r] * rinv[r]);
    }
  }
}

// ---------------------------------------------------------------------------
extern "C" void kernel_launch(void* const* d_in, const int* in_sizes, int n_in,
                              void* d_out, int out_size, void* d_ws,
                              size_t ws_size, hipStream_t stream) {
  const float* x = (const float*)d_in[0];      // [2,2048,1024]
  // d_in[1] token_ids: unused by reference
  const float* w_qkv = (const float*)d_in[2];  // [3072,1024]
  const float* b_qkv = (const float*)d_in[3];  // [3072]
  const float* w_out = (const float*)d_in[4];  // [1024,1024]
  const float* b_out = (const float*)d_in[5];  // [1024]
  float* out = (float*)d_out;                  // [2,2048,1024] fp32

  char* ws = (char*)d_ws;
  unsigned short* xb    = (unsigned short*)(ws + 0);         // 8 MB
  unsigned short* wqkvb = (unsigned short*)(ws + 8388608);   // 6 MB
  unsigned short* woutb = (unsigned short*)(ws + 14680064);  // 2 MB
  unsigned short* Qb    = (unsigned short*)(ws + 16777216);  // 8 MB [bh,s,64]
  unsigned short* Kb    = (unsigned short*)(ws + 25165824);  // 8 MB [bh,s,64]
  unsigned short* Vt    = (unsigned short*)(ws + 33554432);  // 8 MB [bh,d,2048]
  unsigned short* ctxb  = (unsigned short*)(ws + 41943040);  // 8 MB [b,s,1024]

  // fp32 -> bf16 conversions, one launch (grid-stride)
  cvt_all<<<2048, 256, 0, stream>>>(x, w_qkv, w_out, xb, wqkvb, woutb);

  // QKV projection: M=4096, N=3072, K=1024 -> bf16 Q/K/Vt
  // 128^2 tiles, 48 KB LDS -> 3 blocks/CU, all 768 blocks resident
  gemm_qkv<<<dim3(32, 24), 256, 0, stream>>>(xb, wqkvb, b_qkv, Qb, Kb, Vt);

  // sliding attention: 4096 waves (16 queries each), 4 waves/block
  attn_mfma<<<1024, 256, 0, stream>>>(Qb, Kb, Vt, ctxb);

  // out projection: M=4096, N=1024, K=1024 -> fp32 d_out (256 blocks, gny=8)
  gemm_bt<<<256, 256, 0, stream>>>(ctxb, woutb, b_out, out, 4096, 1024, 1024, 8);
}

// Round 13
// 73.899 us; speedup vs baseline: 1.3865x; 1.0109x over previous
//
#include <hip/hip_runtime.h>
#include <stdint.h>

// ---------------------------------------------------------------------------
// SlidingAttentionModule: B=2, S=2048, D=1024, H=16, hd=64, window +-8
//   qkv = x @ w_qkv^T + b_qkv   (128x192 BK=32 3-deep ring GEMM, 512 blocks
//                                = even 2/CU; V written as packed 8B stores)
//   attn: MFMA-tiled 16-query x 32-key sliding window, no max-subtraction
//   out = ctx @ w_out^T + b_out (128^2 BK=64 2-deep R5-proven GEMM, fp32 out)
// ---------------------------------------------------------------------------

typedef __bf16 bf16_t;
typedef bf16_t bf16x8 __attribute__((ext_vector_type(8)));
typedef unsigned short u16x8 __attribute__((ext_vector_type(8)));
typedef float f32x4 __attribute__((ext_vector_type(4)));

#define GLD16(g, l)                                                        \
  __builtin_amdgcn_global_load_lds(                                        \
      (const __attribute__((address_space(1))) void*)(g),                  \
      (__attribute__((address_space(3))) void*)(l), 16, 0, 0)

__device__ __forceinline__ unsigned short f2bf(float f) {
  unsigned int u = __float_as_uint(f);
  u += 0x7FFFu + ((u >> 16) & 1u);  // round-to-nearest-even
  return (unsigned short)(u >> 16);
}

__device__ __forceinline__ bf16x8 ld16(const unsigned short* p) {
  return __builtin_bit_cast(bf16x8, *reinterpret_cast<const u16x8*>(p));
}

// --- fp32 -> bf16 conversion of all three tensors, one launch ---------------
__global__ void cvt_all(const float* __restrict__ x, const float* __restrict__ wq,
                        const float* __restrict__ wo, unsigned short* __restrict__ xb,
                        unsigned short* __restrict__ wqb,
                        unsigned short* __restrict__ wob) {
  const int N0 = 1048576, N1 = 786432, N2 = 262144;  // float4 counts
  for (int i = blockIdx.x * blockDim.x + threadIdx.x; i < N0 + N1 + N2;
       i += gridDim.x * blockDim.x) {
    const float4* src;
    unsigned short* dst;
    int j;
    if (i < N0) { src = (const float4*)x; dst = xb; j = i; }
    else if (i < N0 + N1) { src = (const float4*)wq; dst = wqb; j = i - N0; }
    else { src = (const float4*)wo; dst = wob; j = i - N0 - N1; }
    const float4 f = src[j];
    ushort4 o;
    o.x = f2bf(f.x); o.y = f2bf(f.y); o.z = f2bf(f.z); o.w = f2bf(f.w);
    reinterpret_cast<ushort4*>(dst)[j] = o;
  }
}

// --- 128x192 BK=32 3-deep QKV GEMM ------------------------------------------
// C[m,n] = sum_k A[m,k]*Bt[n,k] + bias[n]; q/k scatter bf16 [bh,s,64];
// V: the 4 acc regs of a fragment are 4 CONSECUTIVE s rows -> pack into one
//    ushort4 (8B) store to Vt [bh,d,2048] (4x fewer V transactions, no LDS).
// Grid 32x16 = 512 blocks = exactly 2/CU (even fill). Staged traffic
// (128+192) rows/tile: 328 MB total vs 384 MB at 128^2 (-15%).
// LDS ring: 3 buf x (A 8KB + B 12KB) = 60 KB -> 2 blocks/CU.
// R10-proven BK=32 swizzle: granule g of row r holds k-chunk g^((r>>1)&3);
// stage unit r: lane u -> row r*64+wave*16+(u>>2), chunk (u&3)^((u>>3)&3),
// dest linear; 4-lane clusters cover one 64B row segment -> coalesced.
// Pipeline: 3 tiles in flight (15 loads), counted vmcnt(10) steady state
// (5/0 at tail), raw barrier pair, stage(t+3) after read-drain.
__global__ __launch_bounds__(256, 2) void gemm_qkv(
    const unsigned short* __restrict__ A,   // [4096,1024] bf16 bits
    const unsigned short* __restrict__ Bt,  // [3072,1024] bf16 bits
    const float* __restrict__ bias,         // [3072]
    unsigned short* __restrict__ Cq, unsigned short* __restrict__ Ck,
    unsigned short* __restrict__ Cv) {
  __shared__ unsigned short smem[30720];  // sA 3x4096 | sB 3x6144 (ushorts)

  const int K = 1024;
  const int tid = threadIdx.x;
  const int wave = tid >> 6;
  const int lane = tid & 63;
  const int m0 = blockIdx.x << 7;   // 32 m-tiles of 128
  const int n0 = blockIdx.y * 192;  // 16 n-tiles of 192

  const int wr = wave >> 1;  // 0..1 (64-row half)
  const int wc = wave & 1;   // 0..1 (96-col half)

  f32x4 acc[4][6] = {};

  // staging source: lane u -> row r*64+wave*16+(u>>2), chunk (u&3)^((u>>3)&3)
  const int srow = (wave << 4) + (lane >> 2);
  const int sslot = (((lane & 3) ^ ((lane >> 3) & 3)) << 3);
  const unsigned short* Ag = A + (size_t)(m0 + srow) * K + sslot;
  const unsigned short* Bg = Bt + (size_t)(n0 + srow) * K + sslot;
  const int wdst = wave * 512;  // ushort offset; +r*2048; +lane*8 implicit

  auto stage = [&](int t, int b) {
#pragma unroll
    for (int r = 0; r < 2; ++r)
      GLD16(Ag + (size_t)(r * 64) * K + t * 32,
            &smem[b * 4096 + r * 2048 + wdst]);
#pragma unroll
    for (int r = 0; r < 3; ++r)
      GLD16(Bg + (size_t)(r * 64) * K + t * 32,
            &smem[12288 + b * 6144 + r * 2048 + wdst]);
  };

  // prologue: 3 K-tiles in flight (15 loads/thread)
  stage(0, 0);
  stage(1, 1);
  stage(2, 2);

  const int qr = lane & 15;
  const int kg = lane >> 4;
  const int geff8 = ((kg ^ ((qr >> 1) & 3)) << 3);
  const int ar = wr * 64 + qr;
  const int br = wc * 96 + qr;

  for (int t = 0; t < 32; ++t) {
    // tile t must land; tiles t+1, t+2 (10 loads) stay in flight
    if (t < 30)
      asm volatile("s_waitcnt vmcnt(10)" ::: "memory");
    else if (t == 30)
      asm volatile("s_waitcnt vmcnt(5)" ::: "memory");
    else
      asm volatile("s_waitcnt vmcnt(0)" ::: "memory");
    __builtin_amdgcn_s_barrier();  // all waves' tile-t loads landed

    const int b = t % 3;
    const unsigned short* sAb = &smem[b * 4096];
    const unsigned short* sBb = &smem[12288 + b * 6144];

    bf16x8 af[4], bf[6];
#pragma unroll
    for (int f = 0; f < 4; ++f) af[f] = ld16(&sAb[(ar + f * 16) * 32 + geff8]);
#pragma unroll
    for (int j = 0; j < 6; ++j) bf[j] = ld16(&sBb[(br + j * 16) * 32 + geff8]);
    asm volatile("s_waitcnt lgkmcnt(0)" ::: "memory");  // frags in regs
    __builtin_amdgcn_sched_barrier(0);                  // rule #18
    __builtin_amdgcn_s_barrier();  // all waves done reading buf b

    if (t + 3 < 32) stage(t + 3, b);  // overwrite safe; hidden by MFMAs

    __builtin_amdgcn_s_setprio(1);
#pragma unroll
    for (int i = 0; i < 4; ++i)
#pragma unroll
      for (int j = 0; j < 6; ++j)
        acc[i][j] = __builtin_amdgcn_mfma_f32_16x16x32_bf16(af[i], bf[j],
                                                            acc[i][j], 0, 0, 0);
    __builtin_amdgcn_s_setprio(0);
  }

  // epilogue: C/D layout col = lane&15, row = (lane>>4)*4 + reg  [m89]
  // regs r=0..3 are consecutive rows (= consecutive s) -> V packs to ushort4.
#pragma unroll
  for (int i = 0; i < 4; ++i) {
    const int row0 = m0 + wr * 64 + i * 16 + ((lane >> 4) << 2);
    const int b2 = row0 >> 11, s0 = row0 & 2047;
#pragma unroll
    for (int j = 0; j < 6; ++j) {
      const int col = n0 + wc * 96 + j * 16 + (lane & 15);
      const float bb = bias[col];
      const int which = col >> 10, nn = col & 1023;
      const int h = nn >> 6, d = nn & 63;
      const int bh = (b2 << 4) + h;
      if (which == 2) {
        ushort4 v4;
        v4.x = f2bf(acc[i][j][0] + bb);
        v4.y = f2bf(acc[i][j][1] + bb);
        v4.z = f2bf(acc[i][j][2] + bb);
        v4.w = f2bf(acc[i][j][3] + bb);
        *reinterpret_cast<ushort4*>(&Cv[((size_t)(bh * 64 + d)) * 2048 + s0]) = v4;
      } else {
        unsigned short* dst = (which == 0) ? Cq : Ck;
#pragma unroll
        for (int r = 0; r < 4; ++r)
          dst[((size_t)(bh * 2048 + s0 + r)) * 64 + d] = f2bf(acc[i][j][r] + bb);
      }
    }
  }
}

// --- 128x128 R5-proven GEMM (out projection, fp32 out) ----------------------
__global__ __launch_bounds__(256, 2) void gemm_bt(
    const unsigned short* __restrict__ A,   // [M,K] bf16 bits
    const unsigned short* __restrict__ Bt,  // [N,K] bf16 bits
    const float* __restrict__ bias,         // [N]
    float* __restrict__ Cp, int M, int N, int K, int gny) {
  __shared__ unsigned short sA[2][8192];
  __shared__ unsigned short sB[2][8192];

  const int tid = threadIdx.x;
  const int wave = tid >> 6;
  const int lane = tid & 63;

  const int nwg = gridDim.x;
  const int bid = blockIdx.x;
  const int cw = (nwg >> 3) / gny;
  const int xcd = bid & 7;
  const int idx = bid >> 3;
  const int m0 = (xcd * cw + idx % cw) * 128;
  const int n0 = (idx / cw) * 128;

  const int wr = wave >> 1;
  const int wc = wave & 1;

  f32x4 acc[4][4] = {};

  const int srow = (wave << 3) + (lane >> 3);
  const int sslot = ((lane & 7) ^ (lane >> 3)) << 3;
  const unsigned short* Ag = A + (size_t)(m0 + srow) * K + sslot;
  const unsigned short* Bg = Bt + (size_t)(n0 + srow) * K + sslot;
  const int wdst = wave * 512;

  const int T = K >> 6;

  auto stage = [&](int t, int b) {
#pragma unroll
    for (int r = 0; r < 4; ++r) {
      GLD16(Ag + (size_t)(r * 32) * K + t * 64, &sA[b][r * 2048 + wdst]);
      GLD16(Bg + (size_t)(r * 32) * K + t * 64, &sB[b][r * 2048 + wdst]);
    }
  };

  stage(0, 0);
  stage(1, 1);

  const int kg = lane >> 4;
  const int l7 = lane & 7;
  const int arr = wr * 64 + (lane & 15);
  const int brr = wc * 64 + (lane & 15);

  for (int t = 0; t < T; ++t) {
    if (t < T - 1)
      asm volatile("s_waitcnt vmcnt(8)" ::: "memory");
    else
      asm volatile("s_waitcnt vmcnt(0)" ::: "memory");
    __builtin_amdgcn_s_barrier();

    const int b = t & 1;
    const unsigned short* sAb = sA[b];
    const unsigned short* sBb = sB[b];
    bf16x8 af[2][4], bfr[2][4];
#pragma unroll
    for (int st = 0; st < 2; ++st) {
#pragma unroll
      for (int f = 0; f < 4; ++f) {
        const int se = ((st << 2) | kg) ^ l7;
        af[st][f] = ld16(&sAb[(arr + f * 16) * 64 + (se << 3)]);
        bfr[st][f] = ld16(&sBb[(brr + f * 16) * 64 + (se << 3)]);
      }
    }
    asm volatile("s_waitcnt lgkmcnt(0)" ::: "memory");
    __builtin_amdgcn_sched_barrier(0);
    __builtin_amdgcn_s_barrier();

    if (t + 2 < T) stage(t + 2, b);

#pragma unroll
    for (int st = 0; st < 2; ++st)
#pragma unroll
      for (int i = 0; i < 4; ++i)
#pragma unroll
        for (int j = 0; j < 4; ++j)
          acc[i][j] = __builtin_amdgcn_mfma_f32_16x16x32_bf16(
              af[st][i], bfr[st][j], acc[i][j], 0, 0, 0);
  }

#pragma unroll
  for (int i = 0; i < 4; ++i) {
    const int row0 = m0 + wr * 64 + i * 16 + ((lane >> 4) << 2);
#pragma unroll
    for (int j = 0; j < 4; ++j) {
      const int col = n0 + wc * 64 + j * 16 + (lane & 15);
      const float bb = bias[col];
#pragma unroll
      for (int r = 0; r < 4; ++r)
        Cp[(size_t)(row0 + r) * N + col] = acc[i][j][r] + bb;
    }
  }
}

// --- MFMA sliding attention: 1 wave = 16 queries x 32-key window ------------
// Q,K: [bh, s, 64] bf16.  Vt: [bh, d, 2048] bf16.  ctx out: [b, s, 1024] bf16.
__global__ __launch_bounds__(256) void attn_mfma(
    const unsigned short* __restrict__ Qb, const unsigned short* __restrict__ Kb,
    const unsigned short* __restrict__ Vt, unsigned short* __restrict__ ctx) {
  __shared__ unsigned short P[4][16][40];  // per-wave P tile, padded stride 40
  const int wave = threadIdx.x >> 6;
  const int lane = threadIdx.x & 63;
  const int gw = (blockIdx.x << 2) + wave;
  const int bh = gw >> 7;           // 0..31
  const int i0 = (gw & 127) << 4;   // query tile start
  const int qr = lane & 15;
  const int kg = lane >> 4;         // 0..3
  const int kc = kg << 3;           // k-offset

  const size_t qbase = ((size_t)(bh * 2048 + i0 + qr)) * 64;
  const bf16x8 aq0 = ld16(Qb + qbase + kc);
  const bf16x8 aq1 = ld16(Qb + qbase + 32 + kc);

  f32x4 sc0 = {0.f, 0.f, 0.f, 0.f}, sc1 = {0.f, 0.f, 0.f, 0.f};
  {
    const int ka0 = i0 - 8 + qr;
    const int ka1 = ka0 + 16;
    const int kcl0 = min(max(ka0, 0), 2047);
    const int kcl1 = min(max(ka1, 0), 2047);
    const unsigned short* K0 = Kb + ((size_t)(bh * 2048 + kcl0)) * 64;
    const unsigned short* K1 = Kb + ((size_t)(bh * 2048 + kcl1)) * 64;
    sc0 = __builtin_amdgcn_mfma_f32_16x16x32_bf16(aq0, ld16(K0 + kc), sc0, 0, 0, 0);
    sc0 = __builtin_amdgcn_mfma_f32_16x16x32_bf16(aq1, ld16(K0 + 32 + kc), sc0, 0, 0, 0);
    sc1 = __builtin_amdgcn_mfma_f32_16x16x32_bf16(aq0, ld16(K1 + kc), sc1, 0, 0, 0);
    sc1 = __builtin_amdgcn_mfma_f32_16x16x32_bf16(aq1, ld16(K1 + 32 + kc), sc1, 0, 0, 0);
  }

  unsigned short* Pw = &P[wave][0][0];
  float lsum[4];
#pragma unroll
  for (int r = 0; r < 4; ++r) {
    const int q = (kg << 2) + r;
    const int key0 = qr, key1 = 16 + qr;
    const int ka0 = i0 - 8 + key0, ka1 = i0 - 8 + key1;
    const bool v0 = (q <= key0) && (key0 <= q + 16) && (ka0 >= 0) && (ka0 < 2048);
    const bool v1 = (q <= key1) && (key1 <= q + 16) && (ka1 >= 0) && (ka1 < 2048);
    const float e0 = v0 ? __expf(sc0[r] * 0.125f) : 0.f;
    const float e1 = v1 ? __expf(sc1[r] * 0.125f) : 0.f;
    Pw[q * 40 + key0] = f2bf(e0);
    Pw[q * 40 + key1] = f2bf(e1);
    float s = e0 + e1;
#pragma unroll
    for (int off = 1; off < 16; off <<= 1) s += __shfl_xor(s, off);
    lsum[r] = s;
  }

  const bf16x8 pa = ld16(&Pw[qr * 40 + kc]);

  const int base_s = min(max(i0 - 8 + kc, 0), 2040);
  f32x4 o[4];
  const f32x4 zero = {0.f, 0.f, 0.f, 0.f};
#pragma unroll
  for (int t2 = 0; t2 < 4; ++t2) {
    const unsigned short* Vr =
        Vt + ((size_t)(bh * 64 + t2 * 16 + qr)) * 2048 + base_s;
    o[t2] = __builtin_amdgcn_mfma_f32_16x16x32_bf16(pa, ld16(Vr), zero, 0, 0, 0);
  }

  const int b = bh >> 4, h = bh & 15;
  float rinv[4];
#pragma unroll
  for (int r = 0; r < 4; ++r) rinv[r] = 1.0f / lsum[r];
#pragma unroll
  for (int t2 = 0; t2 < 4; ++t2) {
#pragma unroll
    for (int r = 0; r < 4; ++r) {
      const int q = (kg << 2) + r;
      const int d = t2 * 16 + qr;
      ctx[((size_t)(b * 2048 + i0 + q)) * 1024 + (h << 6) + d] =
          f2bf(o[t2][r] * rinv[r]);
    }
  }
}

// ---------------------------------------------------------------------------
extern "C" void kernel_launch(void* const* d_in, const int* in_sizes, int n_in,
                              void* d_out, int out_size, void* d_ws,
                              size_t ws_size, hipStream_t stream) {
  const float* x = (const float*)d_in[0];      // [2,2048,1024]
  // d_in[1] token_ids: unused by reference
  const float* w_qkv = (const float*)d_in[2];  // [3072,1024]
  const float* b_qkv = (const float*)d_in[3];  // [3072]
  const float* w_out = (const float*)d_in[4];  // [1024,1024]
  const float* b_out = (const float*)d_in[5];  // [1024]
  float* out = (float*)d_out;                  // [2,2048,1024] fp32

  char* ws = (char*)d_ws;
  unsigned short* xb    = (unsigned short*)(ws + 0);         // 8 MB
  unsigned short* wqkvb = (unsigned short*)(ws + 8388608);   // 6 MB
  unsigned short* woutb = (unsigned short*)(ws + 14680064);  // 2 MB
  unsigned short* Qb    = (unsigned short*)(ws + 16777216);  // 8 MB [bh,s,64]
  unsigned short* Kb    = (unsigned short*)(ws + 25165824);  // 8 MB [bh,s,64]
  unsigned short* Vt    = (unsigned short*)(ws + 33554432);  // 8 MB [bh,d,2048]
  unsigned short* ctxb  = (unsigned short*)(ws + 41943040);  // 8 MB [b,s,1024]

  // fp32 -> bf16 conversions, one launch (grid-stride)
  cvt_all<<<2048, 256, 0, stream>>>(x, w_qkv, w_out, xb, wqkvb, woutb);

  // QKV projection: M=4096, N=3072, K=1024 -> bf16 Q/K/Vt
  // 128x192 tiles: 32 x 16 = 512 blocks, exactly 2/CU
  gemm_qkv<<<dim3(32, 16), 256, 0, stream>>>(xb, wqkvb, b_qkv, Qb, Kb, Vt);

  // sliding attention: 4096 waves (16 queries each), 4 waves/block
  attn_mfma<<<1024, 256, 0, stream>>>(Qb, Kb, Vt, ctxb);

  // out projection: M=4096, N=1024, K=1024 -> fp32 d_out (256 blocks, gny=8)
  gemm_bt<<<256, 256, 0, stream>>>(ctxb, woutb, b_out, out, 4096, 1024, 1024, 8);
}

// Round 14
// 73.859 us; speedup vs baseline: 1.3872x; 1.0005x over previous
//
#include <hip/hip_runtime.h>
#include <stdint.h>

// ---------------------------------------------------------------------------
// SlidingAttentionModule: B=2, S=2048, D=1024, H=16, hd=64, window +-8
//   qkv = x @ w_qkv^T + b_qkv   (128x192 BK=32 4-deep ring GEMM, 512 blocks,
//                                2/CU; V written as packed 8B stores)
//   attn: MFMA-tiled 16-query x 32-key sliding window, no max-subtraction
//   out = ctx @ w_out^T + b_out (128^2 BK=64 2-deep R5-proven GEMM, fp32 out)
// ---------------------------------------------------------------------------

typedef __bf16 bf16_t;
typedef bf16_t bf16x8 __attribute__((ext_vector_type(8)));
typedef unsigned short u16x8 __attribute__((ext_vector_type(8)));
typedef float f32x4 __attribute__((ext_vector_type(4)));

#define GLD16(g, l)                                                        \
  __builtin_amdgcn_global_load_lds(                                        \
      (const __attribute__((address_space(1))) void*)(g),                  \
      (__attribute__((address_space(3))) void*)(l), 16, 0, 0)

__device__ __forceinline__ unsigned short f2bf(float f) {
  unsigned int u = __float_as_uint(f);
  u += 0x7FFFu + ((u >> 16) & 1u);  // round-to-nearest-even
  return (unsigned short)(u >> 16);
}

__device__ __forceinline__ bf16x8 ld16(const unsigned short* p) {
  return __builtin_bit_cast(bf16x8, *reinterpret_cast<const u16x8*>(p));
}

// --- fp32 -> bf16 conversion, 8 floats/thread, 16B stores -------------------
__global__ void cvt_all(const float* __restrict__ x, const float* __restrict__ wq,
                        const float* __restrict__ wo, unsigned short* __restrict__ xb,
                        unsigned short* __restrict__ wqb,
                        unsigned short* __restrict__ wob) {
  // unit = 8 floats. x: 524288 units, wq: 393216, wo: 131072.
  const int N0 = 524288, N1 = 393216, N2 = 131072;
  for (int i = blockIdx.x * blockDim.x + threadIdx.x; i < N0 + N1 + N2;
       i += gridDim.x * blockDim.x) {
    const float4* src;
    unsigned short* dst;
    int j;
    if (i < N0) { src = (const float4*)x; dst = xb; j = i; }
    else if (i < N0 + N1) { src = (const float4*)wq; dst = wqb; j = i - N0; }
    else { src = (const float4*)wo; dst = wob; j = i - N0 - N1; }
    const float4 f0 = src[j * 2];
    const float4 f1 = src[j * 2 + 1];
    u16x8 o;
    o[0] = f2bf(f0.x); o[1] = f2bf(f0.y); o[2] = f2bf(f0.z); o[3] = f2bf(f0.w);
    o[4] = f2bf(f1.x); o[5] = f2bf(f1.y); o[6] = f2bf(f1.z); o[7] = f2bf(f1.w);
    *reinterpret_cast<u16x8*>(&dst[i < N0 ? j * 8 : j * 8]) = o;
  }
}

// --- 128x192 BK=32 4-deep QKV GEMM ------------------------------------------
// C[m,n] = sum_k A[m,k]*Bt[n,k] + bias[n]; q/k scatter bf16 [bh,s,64];
// V: 4 acc regs of a fragment = 4 consecutive s -> one ushort4 (8B) store.
// Grid 32x16 = 512 blocks = exactly 2/CU.
// LDS ring: 4 buf x (A 8KB + B 12KB) = 80 KB -> still 2 blocks/CU.
// R10-proven BK=32 swizzle: granule g of row r holds k-chunk g^((r>>1)&3);
// stage unit r: lane u -> row r*64+wave*16+(u>>2), chunk (u&3)^((u>>3)&3),
// dest linear; 4-lane clusters cover one 64B row segment -> coalesced.
// Pipeline: 4 tiles in flight (20 loads), counted vmcnt(15) steady state
// (10/5/0 tail), raw barrier pair, stage(t+4) after read-drain.
__global__ __launch_bounds__(256, 2) void gemm_qkv(
    const unsigned short* __restrict__ A,   // [4096,1024] bf16 bits
    const unsigned short* __restrict__ Bt,  // [3072,1024] bf16 bits
    const float* __restrict__ bias,         // [3072]
    unsigned short* __restrict__ Cq, unsigned short* __restrict__ Ck,
    unsigned short* __restrict__ Cv) {
  __shared__ unsigned short smem[40960];  // sA 4x4096 | sB 4x6144 (ushorts)

  const int K = 1024;
  const int tid = threadIdx.x;
  const int wave = tid >> 6;
  const int lane = tid & 63;
  const int m0 = blockIdx.x << 7;   // 32 m-tiles of 128
  const int n0 = blockIdx.y * 192;  // 16 n-tiles of 192

  const int wr = wave >> 1;  // 0..1 (64-row half)
  const int wc = wave & 1;   // 0..1 (96-col half)

  f32x4 acc[4][6] = {};

  // staging source: lane u -> row r*64+wave*16+(u>>2), chunk (u&3)^((u>>3)&3)
  const int srow = (wave << 4) + (lane >> 2);
  const int sslot = (((lane & 3) ^ ((lane >> 3) & 3)) << 3);
  const unsigned short* Ag = A + (size_t)(m0 + srow) * K + sslot;
  const unsigned short* Bg = Bt + (size_t)(n0 + srow) * K + sslot;
  const int wdst = wave * 512;  // ushort offset; +r*2048; +lane*8 implicit

  auto stage = [&](int t, int b) {
#pragma unroll
    for (int r = 0; r < 2; ++r)
      GLD16(Ag + (size_t)(r * 64) * K + t * 32,
            &smem[b * 4096 + r * 2048 + wdst]);
#pragma unroll
    for (int r = 0; r < 3; ++r)
      GLD16(Bg + (size_t)(r * 64) * K + t * 32,
            &smem[16384 + b * 6144 + r * 2048 + wdst]);
  };

  // prologue: 4 K-tiles in flight (20 loads/thread)
  stage(0, 0);
  stage(1, 1);
  stage(2, 2);
  stage(3, 3);

  const int qr = lane & 15;
  const int kg = lane >> 4;
  const int geff8 = ((kg ^ ((qr >> 1) & 3)) << 3);
  const int ar = wr * 64 + qr;
  const int br = wc * 96 + qr;

  for (int t = 0; t < 32; ++t) {
    // tile t must land; tiles t+1..t+3 (15 loads) stay in flight
    if (t < 29)
      asm volatile("s_waitcnt vmcnt(15)" ::: "memory");
    else if (t == 29)
      asm volatile("s_waitcnt vmcnt(10)" ::: "memory");
    else if (t == 30)
      asm volatile("s_waitcnt vmcnt(5)" ::: "memory");
    else
      asm volatile("s_waitcnt vmcnt(0)" ::: "memory");
    __builtin_amdgcn_s_barrier();  // all waves' tile-t loads landed

    const int b = t & 3;
    const unsigned short* sAb = &smem[b * 4096];
    const unsigned short* sBb = &smem[16384 + b * 6144];

    bf16x8 af[4], bf[6];
#pragma unroll
    for (int f = 0; f < 4; ++f) af[f] = ld16(&sAb[(ar + f * 16) * 32 + geff8]);
#pragma unroll
    for (int j = 0; j < 6; ++j) bf[j] = ld16(&sBb[(br + j * 16) * 32 + geff8]);
    asm volatile("s_waitcnt lgkmcnt(0)" ::: "memory");  // frags in regs
    __builtin_amdgcn_sched_barrier(0);                  // rule #18
    __builtin_amdgcn_s_barrier();  // all waves done reading buf b

    if (t + 4 < 32) stage(t + 4, b);  // overwrite safe; hidden by MFMAs

    __builtin_amdgcn_s_setprio(1);
#pragma unroll
    for (int i = 0; i < 4; ++i)
#pragma unroll
      for (int j = 0; j < 6; ++j)
        acc[i][j] = __builtin_amdgcn_mfma_f32_16x16x32_bf16(af[i], bf[j],
                                                            acc[i][j], 0, 0, 0);
    __builtin_amdgcn_s_setprio(0);
  }

  // epilogue: C/D layout col = lane&15, row = (lane>>4)*4 + reg  [m89]
  // regs r=0..3 are consecutive rows (= consecutive s) -> V packs to ushort4.
#pragma unroll
  for (int i = 0; i < 4; ++i) {
    const int row0 = m0 + wr * 64 + i * 16 + ((lane >> 4) << 2);
    const int b2 = row0 >> 11, s0 = row0 & 2047;
#pragma unroll
    for (int j = 0; j < 6; ++j) {
      const int col = n0 + wc * 96 + j * 16 + (lane & 15);
      const float bb = bias[col];
      const int which = col >> 10, nn = col & 1023;
      const int h = nn >> 6, d = nn & 63;
      const int bh = (b2 << 4) + h;
      if (which == 2) {
        ushort4 v4;
        v4.x = f2bf(acc[i][j][0] + bb);
        v4.y = f2bf(acc[i][j][1] + bb);
        v4.z = f2bf(acc[i][j][2] + bb);
        v4.w = f2bf(acc[i][j][3] + bb);
        *reinterpret_cast<ushort4*>(&Cv[((size_t)(bh * 64 + d)) * 2048 + s0]) = v4;
      } else {
        unsigned short* dst = (which == 0) ? Cq : Ck;
#pragma unroll
        for (int r = 0; r < 4; ++r)
          dst[((size_t)(bh * 2048 + s0 + r)) * 64 + d] = f2bf(acc[i][j][r] + bb);
      }
    }
  }
}

// --- 128x128 R5-proven GEMM (out projection, fp32 out) ----------------------
__global__ __launch_bounds__(256, 2) void gemm_bt(
    const unsigned short* __restrict__ A,   // [M,K] bf16 bits
    const unsigned short* __restrict__ Bt,  // [N,K] bf16 bits
    const float* __restrict__ bias,         // [N]
    float* __restrict__ Cp, int M, int N, int K, int gny) {
  __shared__ unsigned short sA[2][8192];
  __shared__ unsigned short sB[2][8192];

  const int tid = threadIdx.x;
  const int wave = tid >> 6;
  const int lane = tid & 63;

  const int nwg = gridDim.x;
  const int bid = blockIdx.x;
  const int cw = (nwg >> 3) / gny;
  const int xcd = bid & 7;
  const int idx = bid >> 3;
  const int m0 = (xcd * cw + idx % cw) * 128;
  const int n0 = (idx / cw) * 128;

  const int wr = wave >> 1;
  const int wc = wave & 1;

  f32x4 acc[4][4] = {};

  const int srow = (wave << 3) + (lane >> 3);
  const int sslot = ((lane & 7) ^ (lane >> 3)) << 3;
  const unsigned short* Ag = A + (size_t)(m0 + srow) * K + sslot;
  const unsigned short* Bg = Bt + (size_t)(n0 + srow) * K + sslot;
  const int wdst = wave * 512;

  const int T = K >> 6;

  auto stage = [&](int t, int b) {
#pragma unroll
    for (int r = 0; r < 4; ++r) {
      GLD16(Ag + (size_t)(r * 32) * K + t * 64, &sA[b][r * 2048 + wdst]);
      GLD16(Bg + (size_t)(r * 32) * K + t * 64, &sB[b][r * 2048 + wdst]);
    }
  };

  stage(0, 0);
  stage(1, 1);

  const int kg = lane >> 4;
  const int l7 = lane & 7;
  const int arr = wr * 64 + (lane & 15);
  const int brr = wc * 64 + (lane & 15);

  for (int t = 0; t < T; ++t) {
    if (t < T - 1)
      asm volatile("s_waitcnt vmcnt(8)" ::: "memory");
    else
      asm volatile("s_waitcnt vmcnt(0)" ::: "memory");
    __builtin_amdgcn_s_barrier();

    const int b = t & 1;
    const unsigned short* sAb = sA[b];
    const unsigned short* sBb = sB[b];
    bf16x8 af[2][4], bfr[2][4];
#pragma unroll
    for (int st = 0; st < 2; ++st) {
#pragma unroll
      for (int f = 0; f < 4; ++f) {
        const int se = ((st << 2) | kg) ^ l7;
        af[st][f] = ld16(&sAb[(arr + f * 16) * 64 + (se << 3)]);
        bfr[st][f] = ld16(&sBb[(brr + f * 16) * 64 + (se << 3)]);
      }
    }
    asm volatile("s_waitcnt lgkmcnt(0)" ::: "memory");
    __builtin_amdgcn_sched_barrier(0);
    __builtin_amdgcn_s_barrier();

    if (t + 2 < T) stage(t + 2, b);

#pragma unroll
    for (int st = 0; st < 2; ++st)
#pragma unroll
      for (int i = 0; i < 4; ++i)
#pragma unroll
        for (int j = 0; j < 4; ++j)
          acc[i][j] = __builtin_amdgcn_mfma_f32_16x16x32_bf16(
              af[st][i], bfr[st][j], acc[i][j], 0, 0, 0);
  }

#pragma unroll
  for (int i = 0; i < 4; ++i) {
    const int row0 = m0 + wr * 64 + i * 16 + ((lane >> 4) << 2);
#pragma unroll
    for (int j = 0; j < 4; ++j) {
      const int col = n0 + wc * 64 + j * 16 + (lane & 15);
      const float bb = bias[col];
#pragma unroll
      for (int r = 0; r < 4; ++r)
        Cp[(size_t)(row0 + r) * N + col] = acc[i][j][r] + bb;
    }
  }
}

// --- MFMA sliding attention: 1 wave = 16 queries x 32-key window ------------
// Q,K: [bh, s, 64] bf16.  Vt: [bh, d, 2048] bf16.  ctx out: [b, s, 1024] bf16.
__global__ __launch_bounds__(256) void attn_mfma(
    const unsigned short* __restrict__ Qb, const unsigned short* __restrict__ Kb,
    const unsigned short* __restrict__ Vt, unsigned short* __restrict__ ctx) {
  __shared__ unsigned short P[4][16][40];  // per-wave P tile, padded stride 40
  const int wave = threadIdx.x >> 6;
  const int lane = threadIdx.x & 63;
  const int gw = (blockIdx.x << 2) + wave;
  const int bh = gw >> 7;           // 0..31
  const int i0 = (gw & 127) << 4;   // query tile start
  const int qr = lane & 15;
  const int kg = lane >> 4;         // 0..3
  const int kc = kg << 3;           // k-offset

  const size_t qbase = ((size_t)(bh * 2048 + i0 + qr)) * 64;
  const bf16x8 aq0 = ld16(Qb + qbase + kc);
  const bf16x8 aq1 = ld16(Qb + qbase + 32 + kc);

  f32x4 sc0 = {0.f, 0.f, 0.f, 0.f}, sc1 = {0.f, 0.f, 0.f, 0.f};
  {
    const int ka0 = i0 - 8 + qr;
    const int ka1 = ka0 + 16;
    const int kcl0 = min(max(ka0, 0), 2047);
    const int kcl1 = min(max(ka1, 0), 2047);
    const unsigned short* K0 = Kb + ((size_t)(bh * 2048 + kcl0)) * 64;
    const unsigned short* K1 = Kb + ((size_t)(bh * 2048 + kcl1)) * 64;
    sc0 = __builtin_amdgcn_mfma_f32_16x16x32_bf16(aq0, ld16(K0 + kc), sc0, 0, 0, 0);
    sc0 = __builtin_amdgcn_mfma_f32_16x16x32_bf16(aq1, ld16(K0 + 32 + kc), sc0, 0, 0, 0);
    sc1 = __builtin_amdgcn_mfma_f32_16x16x32_bf16(aq0, ld16(K1 + kc), sc1, 0, 0, 0);
    sc1 = __builtin_amdgcn_mfma_f32_16x16x32_bf16(aq1, ld16(K1 + 32 + kc), sc1, 0, 0, 0);
  }

  unsigned short* Pw = &P[wave][0][0];
  float lsum[4];
#pragma unroll
  for (int r = 0; r < 4; ++r) {
    const int q = (kg << 2) + r;
    const int key0 = qr, key1 = 16 + qr;
    const int ka0 = i0 - 8 + key0, ka1 = i0 - 8 + key1;
    const bool v0 = (q <= key0) && (key0 <= q + 16) && (ka0 >= 0) && (ka0 < 2048);
    const bool v1 = (q <= key1) && (key1 <= q + 16) && (ka1 >= 0) && (ka1 < 2048);
    const float e0 = v0 ? __expf(sc0[r] * 0.125f) : 0.f;
    const float e1 = v1 ? __expf(sc1[r] * 0.125f) : 0.f;
    Pw[q * 40 + key0] = f2bf(e0);
    Pw[q * 40 + key1] = f2bf(e1);
    float s = e0 + e1;
#pragma unroll
    for (int off = 1; off < 16; off <<= 1) s += __shfl_xor(s, off);
    lsum[r] = s;
  }

  const bf16x8 pa = ld16(&Pw[qr * 40 + kc]);

  const int base_s = min(max(i0 - 8 + kc, 0), 2040);
  f32x4 o[4];
  const f32x4 zero = {0.f, 0.f, 0.f, 0.f};
#pragma unroll
  for (int t2 = 0; t2 < 4; ++t2) {
    const unsigned short* Vr =
        Vt + ((size_t)(bh * 64 + t2 * 16 + qr)) * 2048 + base_s;
    o[t2] = __builtin_amdgcn_mfma_f32_16x16x32_bf16(pa, ld16(Vr), zero, 0, 0, 0);
  }

  const int b = bh >> 4, h = bh & 15;
  float rinv[4];
#pragma unroll
  for (int r = 0; r < 4; ++r) rinv[r] = 1.0f / lsum[r];
#pragma unroll
  for (int t2 = 0; t2 < 4; ++t2) {
#pragma unroll
    for (int r = 0; r < 4; ++r) {
      const int q = (kg << 2) + r;
      const int d = t2 * 16 + qr;
      ctx[((size_t)(b * 2048 + i0 + q)) * 1024 + (h << 6) + d] =
          f2bf(o[t2][r] * rinv[r]);
    }
  }
}

// ---------------------------------------------------------------------------
extern "C" void kernel_launch(void* const* d_in, const int* in_sizes, int n_in,
                              void* d_out, int out_size, void* d_ws,
                              size_t ws_size, hipStream_t stream) {
  const float* x = (const float*)d_in[0];      // [2,2048,1024]
  // d_in[1] token_ids: unused by reference
  const float* w_qkv = (const float*)d_in[2];  // [3072,1024]
  const float* b_qkv = (const float*)d_in[3];  // [3072]
  const float* w_out = (const float*)d_in[4];  // [1024,1024]
  const float* b_out = (const float*)d_in[5];  // [1024]
  float* out = (float*)d_out;                  // [2,2048,1024] fp32

  char* ws = (char*)d_ws;
  unsigned short* xb    = (unsigned short*)(ws + 0);         // 8 MB
  unsigned short* wqkvb = (unsigned short*)(ws + 8388608);   // 6 MB
  unsigned short* woutb = (unsigned short*)(ws + 14680064);  // 2 MB
  unsigned short* Qb    = (unsigned short*)(ws + 16777216);  // 8 MB [bh,s,64]
  unsigned short* Kb    = (unsigned short*)(ws + 25165824);  // 8 MB [bh,s,64]
  unsigned short* Vt    = (unsigned short*)(ws + 33554432);  // 8 MB [bh,d,2048]
  unsigned short* ctxb  = (unsigned short*)(ws + 41943040);  // 8 MB [b,s,1024]

  // fp32 -> bf16 conversions, one launch (grid-stride, 16B stores)
  cvt_all<<<2048, 256, 0, stream>>>(x, w_qkv, w_out, xb, wqkvb, woutb);

  // QKV projection: M=4096, N=3072, K=1024 -> bf16 Q/K/Vt
  // 128x192 tiles: 32 x 16 = 512 blocks, exactly 2/CU, 4-deep ring
  gemm_qkv<<<dim3(32, 16), 256, 0, stream>>>(xb, wqkvb, b_qkv, Qb, Kb, Vt);

  // sliding attention: 4096 waves (16 queries each), 4 waves/block
  attn_mfma<<<1024, 256, 0, stream>>>(Qb, Kb, Vt, ctxb);

  // out projection: M=4096, N=1024, K=1024 -> fp32 d_out (256 blocks, gny=8)
  gemm_bt<<<256, 256, 0, stream>>>(ctxb, woutb, b_out, out, 4096, 1024, 1024, 8);
}